// Round 11
// baseline (201.386 us; speedup 1.0000x reference)
//
#include <hip/hip_runtime.h>
#include <hip/hip_bf16.h>

// Problem constants
#define BB 128        // batch
#define NN 100000     // memory bank size
#define DD 256        // feat dim (K)
#define CC 2000       // num classes
#define SS 751        // source classes
#define INVTEMP 20.0f // 1/0.05
#define EPSV 1e-6f

#define HIST_BLOCKS 391    // ceil(100000/256)
#define PREP_BLOCKS 32     // 8192/256 (inputs + inputs2 fragments)
#define COPY_BLOCKS 3125   // NN*8/256 exactly
#define NTILES_MAX 3563    // 2000 + 100000/64 upper bound on padded tiles

typedef __attribute__((ext_vector_type(8))) short bf16x8;
typedef __attribute__((ext_vector_type(8))) unsigned short u16x8;
typedef __attribute__((ext_vector_type(4))) float f32x4;

__device__ __forceinline__ unsigned short f2bf(float x) {
    unsigned int u = __float_as_uint(x);
    u += 0x7fffu + ((u >> 16) & 1u);   // round-to-nearest-even
    return (unsigned short)(u >> 16);
}

__device__ __forceinline__ u16x8 pack8(float4 a, float4 b) {
    u16x8 o;
    o[0] = f2bf(a.x); o[1] = f2bf(a.y); o[2] = f2bf(a.z); o[3] = f2bf(a.w);
    o[4] = f2bf(b.x); o[5] = f2bf(b.y); o[6] = f2bf(b.z); o[7] = f2bf(b.w);
    return o;
}

// ---------------- fused: histogram + input-fragment prep (both input sets) ----------------
// inb: 16B chunk ch = (nr*8 + kc)*64 + l holds row nr*16+(l&15)
// (rows 0..127 inputs, 128..255 inputs2), k = kc*32 + (l>>4)*8 + j.
__global__ __launch_bounds__(256) void hist_prep_kernel(
    const int* __restrict__ labels, int* __restrict__ counts,
    const float* __restrict__ in1, const float* __restrict__ in2,
    unsigned short* __restrict__ inb)
{
    int bid = blockIdx.x;
    if (bid < HIST_BLOCKS) {
        int n = bid * 256 + threadIdx.x;
        if (n < NN) atomicAdd(&counts[labels[n]], 1);
    } else {
        int ch = (bid - HIST_BLOCKS) * 256 + threadIdx.x;  // 0..8191
        if (ch >= 8192) return;
        int l  = ch & 63;
        int kc = (ch >> 6) & 7;
        int nr = ch >> 9;
        int row = nr * 16 + (l & 15);
        const float* src = (row < BB) ? (in1 + (size_t)row * DD)
                                      : (in2 + (size_t)(row - BB) * DD);
        int k0 = kc * 32 + ((l >> 4) << 3);
        u16x8 o;
        #pragma unroll
        for (int j = 0; j < 8; ++j) o[j] = f2bf(src[k0 + j]);
        *(u16x8*)(inb + (size_t)ch * 8) = o;
    }
}

// ---------------- scan: padded (64-aligned) tile geometry + per-tile metadata ----------------
// one block, 256 threads. For each class: tcnt = ceil(cnt/64) tiles. Prefix over tcnt
// gives tile_start[c]; row cursor starts at tile_start*64. tile_meta[t] = (c<<5)|local_j.
__global__ __launch_bounds__(256) void scan_kernel(const int* __restrict__ counts,
                                                   int* __restrict__ tile_start,
                                                   int* __restrict__ cursor,
                                                   int* __restrict__ tile_meta,
                                                   int* __restrict__ ntiles_total,
                                                   float* __restrict__ out) {
    const int PT = 8;
    int tid = threadIdx.x;
    if (tid == 0) { out[0] = 0.f; out[1] = 0.f; }
    int tcnt[PT];
    int tot = 0;
    #pragma unroll
    for (int i = 0; i < PT; ++i) {
        int c = tid * PT + i;
        tcnt[i] = (c < CC) ? ((counts[c] + 63) >> 6) : 0;
        tot += tcnt[i];
    }
    __shared__ int sh[256];
    sh[tid] = tot;
    __syncthreads();
    for (int ofs = 1; ofs < 256; ofs <<= 1) {
        int v = (tid >= ofs) ? sh[tid - ofs] : 0;
        __syncthreads();
        sh[tid] += v;
        __syncthreads();
    }
    if (tid == 255) *ntiles_total = sh[255];
    int run = sh[tid] - tot;
    #pragma unroll
    for (int i = 0; i < PT; ++i) {
        int c = tid * PT + i;
        if (c < CC) {
            tile_start[c] = run;
            cursor[c] = run << 6;          // padded row slot
            for (int j = 0; j < tcnt[i]; ++j)
                tile_meta[run + j] = (c << 5) | j;
        }
        run += tcnt[i];
    }
}

// ---------------- scatter_conv: class-sorted padded bf16 copy + pad-row zeroing ----------------
__global__ __launch_bounds__(256) void scatter_conv(
    const int* __restrict__ labels, int* __restrict__ cursor,
    const float* __restrict__ features, unsigned short* __restrict__ featbf,
    const int* __restrict__ tile_meta, const int* __restrict__ counts,
    const int* __restrict__ ntiles_total)
{
    int bid = blockIdx.x;
    if (bid < COPY_BLOCKS) {
        int t = bid * 256 + threadIdx.x;
        int n = t >> 3;        // bank row (NN*8 threads exactly)
        int g = t & 7;
        int c = labels[n];
        int p = 0;
        if (g == 0) p = atomicAdd(&cursor[c], 1);
        p = __shfl(p, (threadIdx.x & 63) & ~7, 64);   // broadcast leader's slot

        const float4* src = (const float4*)(features + (size_t)n * DD) + g * 8; // 128 B
        unsigned short* dst = featbf + (size_t)p * 256 + g * 32;                // 64 B
        #pragma unroll
        for (int i = 0; i < 4; ++i) {
            float4 a = src[2 * i], b = src[2 * i + 1];
            *(u16x8*)(dst + i * 8) = pack8(a, b);
        }
    } else {
        // zero pad rows of tile t
        int t = bid - COPY_BLOCKS;
        if (t >= *ntiles_total) return;
        int meta = tile_meta[t];
        int c = meta >> 5, jloc = meta & 31;
        int cnt = counts[c];
        int r = threadIdx.x >> 2, q = threadIdx.x & 3;
        if ((jloc << 6) + r < cnt) return;   // real data row
        unsigned short* dst = featbf + (((size_t)t * 64 + r) << 8) + (q << 6); // 128 B
        u16x8 z = (u16x8)0;
        #pragma unroll
        for (int i = 0; i < 8; ++i) *(u16x8*)(dst + i * 8) = z;
    }
}

// ---------------- heavy kernel: NO LDS, NO barriers, NO atomics ----------------
// Grid = NTILES_MAX x 1024 (16 waves). Block t (padded tile, single class):
// wave w covers 16 cols (w<8: inputs -> max/min/sum; w>=8: inputs2 -> sum).
// A fragments loaded DIRECTLY from class-sorted padded bf16 featbf:
// lane l reads row 64t+16ma+(l&15), bytes kc*64+(l>>4)*16 -> lanes {l,l+16,l+32,l+48}
// read consecutive 16B of one row = 64B coalesced, L2/L3-resident.
// Pad rows are exact zeros -> sums need no guard; max/min guarded by cnt.
// Per-tile partials written with plain coalesced stores.
__global__ __launch_bounds__(1024, 4) void mm_kernel(
    const unsigned short* __restrict__ featbf, const unsigned short* __restrict__ inb,
    const int* __restrict__ tile_meta, const int* __restrict__ counts,
    const int* __restrict__ ntiles_total,
    float* __restrict__ part_max, float* __restrict__ part_min,
    float* __restrict__ part_sA, float* __restrict__ part_sB)
{
    const int t = blockIdx.x;
    if (t >= *ntiles_total) return;
    const int tid = threadIdx.x;
    const int w   = tid >> 6;
    const int l   = tid & 63;
    const int meta = tile_meta[t];
    const int c    = meta >> 5;
    const int base_local = (meta & 31) << 6;
    const int cnt  = counts[c];

    // B fragments: wave w's 16 cols = inb fragment row nr = w
    bf16x8 bfr[8];
    #pragma unroll
    for (int kc = 0; kc < 8; ++kc)
        bfr[kc] = *(const bf16x8*)(inb + (((size_t)(w * 8 + kc) * 64 + l) << 3));

    f32x4 acc[4];
    #pragma unroll
    for (int ma = 0; ma < 4; ++ma) acc[ma] = (f32x4){0.f, 0.f, 0.f, 0.f};

    const char* A = (const char*)featbf + ((size_t)t << 15);  // tile base: 64 rows x 512 B
    const int rsel = (l & 15) << 9;
    const int ksel = (l >> 4) << 4;
    #pragma unroll
    for (int kc = 0; kc < 8; ++kc) {
        #pragma unroll
        for (int ma = 0; ma < 4; ++ma) {
            bf16x8 a = *(const bf16x8*)(A + ((16 * ma) << 9) + rsel + (kc << 6) + ksel);
            acc[ma] = __builtin_amdgcn_mfma_f32_16x16x32_bf16(a, bfr[kc], acc[ma], 0, 0, 0);
        }
    }

    // fold: lane l covers col (l&15); rows 16ma + 4*(l>>4) + reg
    const int h4 = (l >> 4) << 2;
    float sm = 0.f, mx = -3.4e38f, mn = 3.4e38f;
    #pragma unroll
    for (int ma = 0; ma < 4; ++ma) {
        #pragma unroll
        for (int reg = 0; reg < 4; ++reg) {
            float v = acc[ma][reg];
            sm += v;                               // pads are exact zeros
            if (w < 8) {
                bool valid = (base_local + 16 * ma + h4 + reg) < cnt;
                if (valid) { mx = fmaxf(mx, v); mn = fminf(mn, v); }
            }
        }
    }
    // cross-lane combine over the 4 k-groups (stride 16, 32)
    sm += __shfl_xor(sm, 16); sm += __shfl_xor(sm, 32);
    if (w < 8) {
        mx = fmaxf(mx, __shfl_xor(mx, 16)); mx = fmaxf(mx, __shfl_xor(mx, 32));
        mn = fminf(mn, __shfl_xor(mn, 16)); mn = fminf(mn, __shfl_xor(mn, 32));
    }
    if (l < 16) {
        size_t p = (size_t)t * 128 + ((w & 7) << 4) + l;
        if (w < 8) { part_max[p] = mx; part_min[p] = mn; part_sA[p] = sm; }
        else       { part_sB[p] = sm; }
    }
}

// ---------------- combine: fold per-tile partials into per-class results ----------------
__global__ __launch_bounds__(128) void combine_kernel(
    const float* __restrict__ part_max, const float* __restrict__ part_min,
    const float* __restrict__ part_sA, const float* __restrict__ part_sB,
    const int* __restrict__ tile_start, const int* __restrict__ counts,
    float* __restrict__ gmax, float* __restrict__ gmin,
    float* __restrict__ simA, float* __restrict__ simB)
{
    const int c   = blockIdx.x;
    const int col = threadIdx.x;
    const int cnt = counts[c];
    const size_t o = (size_t)c * 128 + col;
    if (cnt <= 0) {
        gmax[o] = 0.f; gmin[o] = 0.f; simA[o] = 0.f; simB[o] = 0.f;
        return;
    }
    const int t0 = tile_start[c];
    const int nt = (cnt + 63) >> 6;
    float mx = -3.4e38f, mn = 3.4e38f, sA = 0.f, sB = 0.f;
    for (int j = 0; j < nt; ++j) {
        size_t p = (size_t)(t0 + j) * 128 + col;
        mx = fmaxf(mx, part_max[p]);
        mn = fminf(mn, part_min[p]);
        sA += part_sA[p];
        sB += part_sB[p];
    }
    float icnt = INVTEMP / (float)cnt;
    gmax[o] = mx * INVTEMP;
    gmin[o] = mn * INVTEMP;
    simA[o] = sA * icnt;
    simB[o] = sB * icnt;
}

// ---------------- finalize: losses ----------------

__device__ __forceinline__ float blk_reduce_sum(float v) {
    __shared__ float sh[4];
    int lane = threadIdx.x & 63, w = threadIdx.x >> 6;
    #pragma unroll
    for (int o = 32; o; o >>= 1) v += __shfl_down(v, o, 64);
    __syncthreads();
    if (lane == 0) sh[w] = v;
    __syncthreads();
    return sh[0] + sh[1] + sh[2] + sh[3];
}

__device__ __forceinline__ float blk_reduce_max(float v) {
    __shared__ float sh[4];
    int lane = threadIdx.x & 63, w = threadIdx.x >> 6;
    #pragma unroll
    for (int o = 32; o; o >>= 1) v = fmaxf(v, __shfl_down(v, o, 64));
    __syncthreads();
    if (lane == 0) sh[w] = v;
    __syncthreads();
    return fmaxf(fmaxf(sh[0], sh[1]), fmaxf(sh[2], sh[3]));
}

__global__ __launch_bounds__(256) void finalize_kernel(
    const float* __restrict__ gmax, const float* __restrict__ gmin,
    const float* __restrict__ simA, const float* __restrict__ simB,
    const int* __restrict__ counts, const int* __restrict__ labels,
    const int* __restrict__ indexes, float* __restrict__ out)
{
    const int b   = blockIdx.x;
    const int tid = threadIdx.x;
    const int tgt = labels[indexes[b]];

    __shared__ float sh_etgt;
    float local = 0.f;
    for (int c = tid; c < CC; c += 256) {
        float e = 0.f;
        if (counts[c] > 0) {
            float v = (c == tgt) ? gmin[(size_t)c * 128 + b] : gmax[(size_t)c * 128 + b];
            e = expf(v);
        }
        local += e;
        if (c == tgt) sh_etgt = e;
    }
    float sum_e = blk_reduce_sum(local);
    float etgt = sh_etgt;
    float loss_con_b = -logf(etgt / (sum_e + EPSV) + EPSV);

    __shared__ float a1[SS], a2[SS];
    for (int c = tid; c < SS; c += 256) {
        a1[c] = simA[(size_t)c * 128 + b];
        a2[c] = simB[(size_t)c * 128 + b];
    }
    __syncthreads();
    float m1 = -3.4e38f, m2 = -3.4e38f;
    for (int c = tid; c < SS; c += 256) { m1 = fmaxf(m1, a1[c]); m2 = fmaxf(m2, a2[c]); }
    m1 = blk_reduce_max(m1);
    m2 = blk_reduce_max(m2);
    float s1 = 0.f, s2 = 0.f;
    for (int c = tid; c < SS; c += 256) { s1 += expf(a1[c] - m1); s2 += expf(a2[c] - m2); }
    s1 = blk_reduce_sum(s1);
    s2 = blk_reduce_sum(s2);
    float inv1 = 1.f / s1, inv2 = 1.f / s2;
    float dsum = 0.f;
    for (int c = tid; c < SS; c += 256) {
        float d = expf(a1[c] - m1) * inv1 - expf(a2[c] - m2) * inv2;
        dsum += d * d;
    }
    dsum = blk_reduce_sum(dsum);
    if (tid == 0) {
        atomicAdd(&out[0], loss_con_b * (1.0f / (float)BB));
        atomicAdd(&out[1], dsum * (1.0f / (float)SS));
    }
}

// ---------------- launch ----------------

extern "C" void kernel_launch(void* const* d_in, const int* in_sizes, int n_in,
                              void* d_out, int out_size, void* d_ws, size_t ws_size,
                              hipStream_t stream) {
    const float* inputs   = (const float*)d_in[0];
    const float* inputs2  = (const float*)d_in[1];
    const float* features = (const float*)d_in[2];
    const int*   labels   = (const int*)d_in[3];
    const int*   indexes  = (const int*)d_in[4];

    float* out = (float*)d_out;

    // workspace layout (int-element offsets)
    int* wsi = (int*)d_ws;
    int* counts     = wsi;                                  // [0, 2048)
    int* tile_start = wsi + 2048;                           // [2048, 4096)
    int* cursor     = wsi + 4096;                           // [4096, 6144)
    int* ntiles     = wsi + 6144;                           // [6144, 6160) (padded)
    unsigned short* inb = (unsigned short*)(wsi + 6160);    // 65536 ushorts -> [6160, 38928)
    int* tile_meta  = wsi + 38928;                          // NTILES_MAX -> [38928, 42491), pad to 42496
    float* part_max = (float*)(wsi + 42496);                // NTILES_MAX*128 floats each
    float* part_min = part_max + (size_t)NTILES_MAX * 128;
    float* part_sA  = part_min + (size_t)NTILES_MAX * 128;
    float* part_sB  = part_sA  + (size_t)NTILES_MAX * 128;
    float* gmax = part_sB + (size_t)NTILES_MAX * 128;       // CC*128 each
    float* gmin = gmax + (size_t)CC * 128;
    float* simA = gmin + (size_t)CC * 128;
    float* simB = simA + (size_t)CC * 128;
    unsigned short* featbf = (unsigned short*)(simB + (size_t)CC * 128); // up to 116.8 MB

    hipMemsetAsync(counts, 0, 2048 * sizeof(int), stream);

    hist_prep_kernel<<<HIST_BLOCKS + PREP_BLOCKS, 256, 0, stream>>>(
        labels, counts, inputs, inputs2, inb);
    scan_kernel<<<1, 256, 0, stream>>>(counts, tile_start, cursor, tile_meta, ntiles, out);
    scatter_conv<<<COPY_BLOCKS + NTILES_MAX, 256, 0, stream>>>(
        labels, cursor, features, featbf, tile_meta, counts, ntiles);
    mm_kernel<<<NTILES_MAX, 1024, 0, stream>>>(featbf, inb, tile_meta, counts, ntiles,
                                               part_max, part_min, part_sA, part_sB);
    combine_kernel<<<CC, 128, 0, stream>>>(part_max, part_min, part_sA, part_sB,
                                           tile_start, counts, gmax, gmin, simA, simB);
    finalize_kernel<<<BB, 256, 0, stream>>>(gmax, gmin, simA, simB, counts,
                                            labels, indexes, out);
}

// Round 12
// 103.432 us; speedup vs baseline: 1.9470x; 1.9470x over previous
//
#include <hip/hip_runtime.h>
#include <hip/hip_bf16.h>

// Problem constants
#define BB 128        // batch
#define NN 100000     // memory bank size
#define DD 256        // feat dim (K)
#define CC 2000       // num classes
#define SS 751        // source classes
#define INVTEMP 20.0f // 1/0.05
#define EPSV 1e-6f

#define HIST_BLOCKS 391    // ceil(100000/256)
#define PREP_BLOCKS 32     // 8192/256 (inputs + inputs2 fragments)
#define COPY_BLOCKS 3125   // NN*8/256 exactly
#define NTILES_MAX 3563    // 2000 + 100000/64 upper bound on padded tiles

typedef __attribute__((ext_vector_type(8))) short bf16x8;
typedef __attribute__((ext_vector_type(8))) unsigned short u16x8;
typedef __attribute__((ext_vector_type(4))) float f32x4;

__device__ __forceinline__ unsigned short f2bf(float x) {
    unsigned int u = __float_as_uint(x);
    u += 0x7fffu + ((u >> 16) & 1u);   // round-to-nearest-even
    return (unsigned short)(u >> 16);
}

__device__ __forceinline__ u16x8 pack8(float4 a, float4 b) {
    u16x8 o;
    o[0] = f2bf(a.x); o[1] = f2bf(a.y); o[2] = f2bf(a.z); o[3] = f2bf(a.w);
    o[4] = f2bf(b.x); o[5] = f2bf(b.y); o[6] = f2bf(b.z); o[7] = f2bf(b.w);
    return o;
}

// ---------------- fused: histogram + input-fragment prep (both input sets) ----------------
// inb: 16B chunk ch = (nr*8 + kc)*64 + l holds row nr*16+(l&15)
// (rows 0..127 inputs, 128..255 inputs2), k = kc*32 + (l>>4)*8 + j.
__global__ __launch_bounds__(256) void hist_prep_kernel(
    const int* __restrict__ labels, int* __restrict__ counts,
    const float* __restrict__ in1, const float* __restrict__ in2,
    unsigned short* __restrict__ inb)
{
    int bid = blockIdx.x;
    if (bid < HIST_BLOCKS) {
        int n = bid * 256 + threadIdx.x;
        if (n < NN) atomicAdd(&counts[labels[n]], 1);
    } else {
        int ch = (bid - HIST_BLOCKS) * 256 + threadIdx.x;  // 0..8191
        if (ch >= 8192) return;
        int l  = ch & 63;
        int kc = (ch >> 6) & 7;
        int nr = ch >> 9;
        int row = nr * 16 + (l & 15);
        const float* src = (row < BB) ? (in1 + (size_t)row * DD)
                                      : (in2 + (size_t)(row - BB) * DD);
        int k0 = kc * 32 + ((l >> 4) << 3);
        u16x8 o;
        #pragma unroll
        for (int j = 0; j < 8; ++j) o[j] = f2bf(src[k0 + j]);
        *(u16x8*)(inb + (size_t)ch * 8) = o;
    }
}

// ---------------- scan: padded (64-aligned) tile geometry + per-tile metadata ----------------
__global__ __launch_bounds__(256) void scan_kernel(const int* __restrict__ counts,
                                                   int* __restrict__ tile_start,
                                                   int* __restrict__ cursor,
                                                   int* __restrict__ tile_meta,
                                                   int* __restrict__ ntiles_total,
                                                   float* __restrict__ out) {
    const int PT = 8;
    int tid = threadIdx.x;
    if (tid == 0) { out[0] = 0.f; out[1] = 0.f; }
    int tcnt[PT];
    int tot = 0;
    #pragma unroll
    for (int i = 0; i < PT; ++i) {
        int c = tid * PT + i;
        tcnt[i] = (c < CC) ? ((counts[c] + 63) >> 6) : 0;
        tot += tcnt[i];
    }
    __shared__ int sh[256];
    sh[tid] = tot;
    __syncthreads();
    for (int ofs = 1; ofs < 256; ofs <<= 1) {
        int v = (tid >= ofs) ? sh[tid - ofs] : 0;
        __syncthreads();
        sh[tid] += v;
        __syncthreads();
    }
    if (tid == 255) *ntiles_total = sh[255];
    int run = sh[tid] - tot;
    #pragma unroll
    for (int i = 0; i < PT; ++i) {
        int c = tid * PT + i;
        if (c < CC) {
            tile_start[c] = run;
            cursor[c] = run << 6;          // padded row slot
            for (int j = 0; j < tcnt[i]; ++j)
                tile_meta[run + j] = (c << 5) | j;
        }
        run += tcnt[i];
    }
}

// ---------------- scatter_conv: class-sorted padded bf16 copy (pads left as-is) ----------------
__global__ __launch_bounds__(256) void scatter_conv(
    const int* __restrict__ labels, int* __restrict__ cursor,
    const float* __restrict__ features, unsigned short* __restrict__ featbf)
{
    int t = blockIdx.x * 256 + threadIdx.x;
    int n = t >> 3;        // bank row (NN*8 threads exactly)
    int g = t & 7;
    int c = labels[n];
    int p = 0;
    if (g == 0) p = atomicAdd(&cursor[c], 1);
    p = __shfl(p, (threadIdx.x & 63) & ~7, 64);   // broadcast leader's slot

    const float4* src = (const float4*)(features + (size_t)n * DD) + g * 8; // 128 B
    unsigned short* dst = featbf + (size_t)p * 256 + g * 32;                // 64 B
    #pragma unroll
    for (int i = 0; i < 4; ++i) {
        float4 a = src[2 * i], b = src[2 * i + 1];
        *(u16x8*)(dst + i * 8) = pack8(a, b);
    }
}

// ---------------- heavy kernel: LDS-staged tile, one barrier, no atomics ----------------
// Grid = NTILES_MAX x 512 (8 waves). Block t (padded tile, single class):
// wave w covers 32 cols (w<4: inputs -> max/min/sum; w>=4: inputs2 -> sum).
// Stage: 32 global_load_lds (16B) -> fragment-order LDS, tile read ONCE from L3
// (r11 lesson: direct per-wave global reads = 16x redundant = L3-BW-bound).
// Source pre-applies the XOR swizzle; dest linear (both-sides-or-neither, r8-proven
// conflict-free read). No register staging -> ~112 unified regs, (512,4) no spill,
// 2 blocks/CU. Pad rows hold garbage: fold guards sum AND max/min by row validity.
__global__ __launch_bounds__(512, 4) void mm_kernel(
    const unsigned short* __restrict__ featbf, const unsigned short* __restrict__ inb,
    const int* __restrict__ tile_meta, const int* __restrict__ counts,
    const int* __restrict__ ntiles_total,
    float* __restrict__ part_max, float* __restrict__ part_min,
    float* __restrict__ part_sA, float* __restrict__ part_sB)
{
    const int t = blockIdx.x;
    if (t >= *ntiles_total) return;
    const int tid = threadIdx.x;
    const int w   = tid >> 6;
    const int l   = tid & 63;
    const int meta = tile_meta[t];
    const int c    = meta >> 5;
    const int base_local = (meta & 31) << 6;
    const int cnt  = counts[c];

    __shared__ __align__(16) char ldsA[32768];   // A tile, bf16 fragment order

    // B fragments: wave w -> 32 cols; nr = 2w+nb (0..7 inputs, 8..15 inputs2)
    bf16x8 bfr[16];
    #pragma unroll
    for (int kc = 0; kc < 8; ++kc)
        #pragma unroll
        for (int nb = 0; nb < 2; ++nb) {
            int nr = 2 * w + nb;
            bfr[kc * 2 + nb] = *(const bf16x8*)(inb + (((size_t)(nr * 8 + kc) * 64 + l) << 3));
        }

    // stage A: wave w stages fragments f = 4w..4w+3 (frag f = ma*8+kc)
    const char* Abase = (const char*)featbf + ((size_t)t << 15);  // 64 rows x 512 B
    #pragma unroll
    for (int i = 0; i < 4; ++i) {
        int f   = w * 4 + i;
        int kc  = f & 7;
        int row = ((f >> 3) << 4) + ((l & 15) ^ kc);
        const char* src = Abase + (row << 9) + (kc << 6) + ((l >> 4) << 4);
        __builtin_amdgcn_global_load_lds(
            (const __attribute__((address_space(1))) void*)src,
            (__attribute__((address_space(3))) void*)(&ldsA[0] + (f << 10)),
            16, 0, 0);
    }
    __syncthreads();

    // MFMA: acc[ma][nb]
    f32x4 acc[4][2];
    #pragma unroll
    for (int ma = 0; ma < 4; ++ma)
        #pragma unroll
        for (int nb = 0; nb < 2; ++nb)
            acc[ma][nb] = (f32x4){0.f, 0.f, 0.f, 0.f};

    __builtin_amdgcn_s_setprio(1);
    #pragma unroll
    for (int kc = 0; kc < 8; ++kc) {
        int lx = (l ^ kc) << 4;
        #pragma unroll
        for (int ma = 0; ma < 4; ++ma) {
            bf16x8 a = *(const bf16x8*)(&ldsA[0] + ((ma * 8 + kc) << 10) + lx);
            acc[ma][0] = __builtin_amdgcn_mfma_f32_16x16x32_bf16(a, bfr[kc * 2 + 0], acc[ma][0], 0, 0, 0);
            acc[ma][1] = __builtin_amdgcn_mfma_f32_16x16x32_bf16(a, bfr[kc * 2 + 1], acc[ma][1], 0, 0, 0);
        }
    }
    __builtin_amdgcn_s_setprio(0);

    // fold (guard EVERYTHING by row validity: pads are garbage, not zeros)
    const int h4 = (l >> 4) << 2;
    float sm[2] = {0.f, 0.f};
    float mx[2] = {-3.4e38f, -3.4e38f};
    float mn[2] = { 3.4e38f,  3.4e38f};
    #pragma unroll
    for (int ma = 0; ma < 4; ++ma) {
        #pragma unroll
        for (int reg = 0; reg < 4; ++reg) {
            bool valid = (base_local + 16 * ma + h4 + reg) < cnt;
            if (valid) {
                #pragma unroll
                for (int nb = 0; nb < 2; ++nb) {
                    float v = acc[ma][nb][reg];
                    sm[nb] += v;
                    if (w < 4) {
                        mx[nb] = fmaxf(mx[nb], v);
                        mn[nb] = fminf(mn[nb], v);
                    }
                }
            }
        }
    }
    // cross-lane combine over the 4 k-groups (stride 16, 32)
    #pragma unroll
    for (int nb = 0; nb < 2; ++nb) {
        sm[nb] += __shfl_xor(sm[nb], 16);
        sm[nb] += __shfl_xor(sm[nb], 32);
        if (w < 4) {
            mx[nb] = fmaxf(mx[nb], __shfl_xor(mx[nb], 16));
            mx[nb] = fmaxf(mx[nb], __shfl_xor(mx[nb], 32));
            mn[nb] = fminf(mn[nb], __shfl_xor(mn[nb], 16));
            mn[nb] = fminf(mn[nb], __shfl_xor(mn[nb], 32));
        }
    }
    if (l < 16) {
        #pragma unroll
        for (int nb = 0; nb < 2; ++nb) {
            int col = 32 * (w & 3) + 16 * nb + l;   // 0..127 within its set
            size_t p = (size_t)t * 128 + col;
            if (w < 4) { part_max[p] = mx[nb]; part_min[p] = mn[nb]; part_sA[p] = sm[nb]; }
            else       { part_sB[p] = sm[nb]; }
        }
    }
}

// ---------------- combine: fold per-tile partials into per-class results ----------------
__global__ __launch_bounds__(128) void combine_kernel(
    const float* __restrict__ part_max, const float* __restrict__ part_min,
    const float* __restrict__ part_sA, const float* __restrict__ part_sB,
    const int* __restrict__ tile_start, const int* __restrict__ counts,
    float* __restrict__ gmax, float* __restrict__ gmin,
    float* __restrict__ simA, float* __restrict__ simB)
{
    const int c   = blockIdx.x;
    const int col = threadIdx.x;
    const int cnt = counts[c];
    const size_t o = (size_t)c * 128 + col;
    if (cnt <= 0) {
        gmax[o] = 0.f; gmin[o] = 0.f; simA[o] = 0.f; simB[o] = 0.f;
        return;
    }
    const int t0 = tile_start[c];
    const int nt = (cnt + 63) >> 6;
    float mx = -3.4e38f, mn = 3.4e38f, sA = 0.f, sB = 0.f;
    for (int j = 0; j < nt; ++j) {
        size_t p = (size_t)(t0 + j) * 128 + col;
        mx = fmaxf(mx, part_max[p]);
        mn = fminf(mn, part_min[p]);
        sA += part_sA[p];
        sB += part_sB[p];
    }
    float icnt = INVTEMP / (float)cnt;
    gmax[o] = mx * INVTEMP;
    gmin[o] = mn * INVTEMP;
    simA[o] = sA * icnt;
    simB[o] = sB * icnt;
}

// ---------------- finalize: losses ----------------

__device__ __forceinline__ float blk_reduce_sum(float v) {
    __shared__ float sh[4];
    int lane = threadIdx.x & 63, w = threadIdx.x >> 6;
    #pragma unroll
    for (int o = 32; o; o >>= 1) v += __shfl_down(v, o, 64);
    __syncthreads();
    if (lane == 0) sh[w] = v;
    __syncthreads();
    return sh[0] + sh[1] + sh[2] + sh[3];
}

__device__ __forceinline__ float blk_reduce_max(float v) {
    __shared__ float sh[4];
    int lane = threadIdx.x & 63, w = threadIdx.x >> 6;
    #pragma unroll
    for (int o = 32; o; o >>= 1) v = fmaxf(v, __shfl_down(v, o, 64));
    __syncthreads();
    if (lane == 0) sh[w] = v;
    __syncthreads();
    return fmaxf(fmaxf(sh[0], sh[1]), fmaxf(sh[2], sh[3]));
}

__global__ __launch_bounds__(256) void finalize_kernel(
    const float* __restrict__ gmax, const float* __restrict__ gmin,
    const float* __restrict__ simA, const float* __restrict__ simB,
    const int* __restrict__ counts, const int* __restrict__ labels,
    const int* __restrict__ indexes, float* __restrict__ out)
{
    const int b   = blockIdx.x;
    const int tid = threadIdx.x;
    const int tgt = labels[indexes[b]];

    __shared__ float sh_etgt;
    float local = 0.f;
    for (int c = tid; c < CC; c += 256) {
        float e = 0.f;
        if (counts[c] > 0) {
            float v = (c == tgt) ? gmin[(size_t)c * 128 + b] : gmax[(size_t)c * 128 + b];
            e = expf(v);
        }
        local += e;
        if (c == tgt) sh_etgt = e;
    }
    float sum_e = blk_reduce_sum(local);
    float etgt = sh_etgt;
    float loss_con_b = -logf(etgt / (sum_e + EPSV) + EPSV);

    __shared__ float a1[SS], a2[SS];
    for (int c = tid; c < SS; c += 256) {
        a1[c] = simA[(size_t)c * 128 + b];
        a2[c] = simB[(size_t)c * 128 + b];
    }
    __syncthreads();
    float m1 = -3.4e38f, m2 = -3.4e38f;
    for (int c = tid; c < SS; c += 256) { m1 = fmaxf(m1, a1[c]); m2 = fmaxf(m2, a2[c]); }
    m1 = blk_reduce_max(m1);
    m2 = blk_reduce_max(m2);
    float s1 = 0.f, s2 = 0.f;
    for (int c = tid; c < SS; c += 256) { s1 += expf(a1[c] - m1); s2 += expf(a2[c] - m2); }
    s1 = blk_reduce_sum(s1);
    s2 = blk_reduce_sum(s2);
    float inv1 = 1.f / s1, inv2 = 1.f / s2;
    float dsum = 0.f;
    for (int c = tid; c < SS; c += 256) {
        float d = expf(a1[c] - m1) * inv1 - expf(a2[c] - m2) * inv2;
        dsum += d * d;
    }
    dsum = blk_reduce_sum(dsum);
    if (tid == 0) {
        atomicAdd(&out[0], loss_con_b * (1.0f / (float)BB));
        atomicAdd(&out[1], dsum * (1.0f / (float)SS));
    }
}

// ---------------- launch ----------------

extern "C" void kernel_launch(void* const* d_in, const int* in_sizes, int n_in,
                              void* d_out, int out_size, void* d_ws, size_t ws_size,
                              hipStream_t stream) {
    const float* inputs   = (const float*)d_in[0];
    const float* inputs2  = (const float*)d_in[1];
    const float* features = (const float*)d_in[2];
    const int*   labels   = (const int*)d_in[3];
    const int*   indexes  = (const int*)d_in[4];

    float* out = (float*)d_out;

    // workspace layout (int-element offsets)
    int* wsi = (int*)d_ws;
    int* counts     = wsi;                                  // [0, 2048)
    int* tile_start = wsi + 2048;                           // [2048, 4096)
    int* cursor     = wsi + 4096;                           // [4096, 6144)
    int* ntiles     = wsi + 6144;                           // [6144, 6160)
    unsigned short* inb = (unsigned short*)(wsi + 6160);    // 65536 ushorts -> [6160, 38928)
    int* tile_meta  = wsi + 38928;                          // NTILES_MAX -> pad to 42496
    float* part_max = (float*)(wsi + 42496);                // NTILES_MAX*128 floats each
    float* part_min = part_max + (size_t)NTILES_MAX * 128;
    float* part_sA  = part_min + (size_t)NTILES_MAX * 128;
    float* part_sB  = part_sA  + (size_t)NTILES_MAX * 128;
    float* gmax = part_sB + (size_t)NTILES_MAX * 128;       // CC*128 each
    float* gmin = gmax + (size_t)CC * 128;
    float* simA = gmin + (size_t)CC * 128;
    float* simB = simA + (size_t)CC * 128;
    unsigned short* featbf = (unsigned short*)(simB + (size_t)CC * 128); // up to 116.8 MB

    hipMemsetAsync(counts, 0, 2048 * sizeof(int), stream);

    hist_prep_kernel<<<HIST_BLOCKS + PREP_BLOCKS, 256, 0, stream>>>(
        labels, counts, inputs, inputs2, inb);
    scan_kernel<<<1, 256, 0, stream>>>(counts, tile_start, cursor, tile_meta, ntiles, out);
    scatter_conv<<<COPY_BLOCKS, 256, 0, stream>>>(labels, cursor, features, featbf);
    mm_kernel<<<NTILES_MAX, 512, 0, stream>>>(featbf, inb, tile_meta, counts, ntiles,
                                              part_max, part_min, part_sA, part_sB);
    combine_kernel<<<CC, 128, 0, stream>>>(part_max, part_min, part_sA, part_sB,
                                           tile_start, counts, gmax, gmin, simA, simB);
    finalize_kernel<<<BB, 256, 0, stream>>>(gmax, gmin, simA, simB, counts,
                                            labels, indexes, out);
}